// Round 1
// baseline (475.571 us; speedup 1.0000x reference)
//
#include <hip/hip_runtime.h>
#include <math.h>

#define H      1024
#define I2     2048
#define G3     3072
#define SRC    4096
#define VOCAB  32000

// d_out layout: [0,32000) log_softmax | [32000,33024) attn_context
//               [33024,34048) h_new   | [34048,38144) attn_weights
#define OUT_CTX   32000
#define OUT_HID   33024
#define OUT_ATTW  34048

// ws layout (floats)
#define WS_GI     0        // 3072
#define WS_GH     3072     // 3072
#define WS_HNEW   6144     // 1024
#define WS_SCORES 7168     // 4096
#define WS_ATTW   11264    // 4096
#define WS_CTX    15360    // 1024
#define WS_LOGITS 16384    // 32000
#define WS_STATS  48384    // 1 (logsumexp)

__device__ __forceinline__ float wave_reduce_sum(float v) {
    #pragma unroll
    for (int off = 32; off > 0; off >>= 1)
        v += __shfl_down(v, off, 64);
    return v;
}

__device__ __forceinline__ float wave_reduce_max(float v) {
    #pragma unroll
    for (int off = 32; off > 0; off >>= 1)
        v = fmaxf(v, __shfl_down(v, off, 64));
    return v;
}

// A: gi[j] = W_ih[j,:]@rnn_in + b_ih[j];  gh[j] = W_hh[j,:]@h + b_hh[j]
// one block (256 thr) per row j in [0,3072)
__global__ void gru_matvec_kernel(const int* __restrict__ word,
                                  const float* __restrict__ last_ctx,
                                  const float* __restrict__ prev_h,
                                  const float* __restrict__ emb,
                                  const float* __restrict__ W_ih,
                                  const float* __restrict__ W_hh,
                                  const float* __restrict__ b_ih,
                                  const float* __restrict__ b_hh,
                                  float* __restrict__ ws) {
    __shared__ float lds[8];
    const int j = blockIdx.x;
    const int tid = threadIdx.x;
    const int w = word[0];
    const float4* emb4 = (const float4*)(emb + (long)w * H);
    const float4* ctx4 = (const float4*)last_ctx;
    const float4* h4   = (const float4*)prev_h;

    // gi: row of W_ih (2048 f32 = 512 float4), 2 float4 per thread
    const float4* Wi = (const float4*)(W_ih + (long)j * I2);
    float gi = 0.f;
    {
        float4 wv = Wi[tid];            // elems [0,1024) -> emb row
        float4 xv = emb4[tid];
        gi += wv.x*xv.x + wv.y*xv.y + wv.z*xv.z + wv.w*xv.w;
        wv = Wi[tid + 256];             // elems [1024,2048) -> last_context
        xv = ctx4[tid];
        gi += wv.x*xv.x + wv.y*xv.y + wv.z*xv.z + wv.w*xv.w;
    }
    // gh: row of W_hh (1024 f32 = 256 float4), 1 float4 per thread
    const float4* Wh = (const float4*)(W_hh + (long)j * H);
    float gh;
    {
        float4 wv = Wh[tid];
        float4 hv = h4[tid];
        gh = wv.x*hv.x + wv.y*hv.y + wv.z*hv.z + wv.w*hv.w;
    }

    const int lane = tid & 63, wid = tid >> 6;
    gi = wave_reduce_sum(gi);
    gh = wave_reduce_sum(gh);
    if (lane == 0) { lds[wid] = gi; lds[4 + wid] = gh; }
    __syncthreads();
    if (tid == 0) {
        float gis = lds[0] + lds[1] + lds[2] + lds[3];
        float ghs = lds[4] + lds[5] + lds[6] + lds[7];
        ws[WS_GI + j] = gis + b_ih[j];
        ws[WS_GH + j] = ghs + b_hh[j];
    }
}

// B: GRU gates -> h_new (1 block, 1024 threads)
__global__ void gru_gates_kernel(const float* __restrict__ prev_h,
                                 float* __restrict__ ws,
                                 float* __restrict__ out_hid) {
    const int j = threadIdx.x;
    const float ir = ws[WS_GI + j],        hr = ws[WS_GH + j];
    const float iz = ws[WS_GI + H + j],    hz = ws[WS_GH + H + j];
    const float in_ = ws[WS_GI + 2*H + j], hn = ws[WS_GH + 2*H + j];
    const float r = 1.f / (1.f + expf(-(ir + hr)));
    const float z = 1.f / (1.f + expf(-(iz + hz)));
    const float n = tanhf(in_ + r * hn);
    const float h = prev_h[j];
    const float hnew = (1.f - z) * n + z * h;
    ws[WS_HNEW + j] = hnew;
    out_hid[j] = hnew;
}

// C: scores[s] = enc[s,:] @ h_new  — one block (256 thr) per s
__global__ void attn_scores_kernel(const float* __restrict__ enc,
                                   const float* __restrict__ ws_in,
                                   float* __restrict__ ws) {
    __shared__ float lds[4];
    const int s = blockIdx.x, tid = threadIdx.x;
    float4 ev = ((const float4*)(enc + (long)s * H))[tid];
    float4 hv = ((const float4*)(ws_in + WS_HNEW))[tid];
    float d = ev.x*hv.x + ev.y*hv.y + ev.z*hv.z + ev.w*hv.w;
    const int lane = tid & 63, wid = tid >> 6;
    d = wave_reduce_sum(d);
    if (lane == 0) lds[wid] = d;
    __syncthreads();
    if (tid == 0) ws[WS_SCORES + s] = lds[0] + lds[1] + lds[2] + lds[3];
}

// D: softmax over 4096 scores; write weights to ws + d_out; zero ctx accum
__global__ void attn_softmax_kernel(float* __restrict__ ws,
                                    float* __restrict__ out_attw) {
    __shared__ float lds[16];
    __shared__ float s_max, s_sum;
    const int tid = threadIdx.x;          // 1024 threads, 4 scores each
    const int lane = tid & 63, wid = tid >> 6;
    float4 sv = ((const float4*)(ws + WS_SCORES))[tid];
    float m = fmaxf(fmaxf(sv.x, sv.y), fmaxf(sv.z, sv.w));
    m = wave_reduce_max(m);
    if (lane == 0) lds[wid] = m;
    __syncthreads();
    if (tid == 0) {
        float mm = lds[0];
        #pragma unroll
        for (int i = 1; i < 16; ++i) mm = fmaxf(mm, lds[i]);
        s_max = mm;
    }
    __syncthreads();
    const float mx = s_max;
    float4 e;
    e.x = expf(sv.x - mx); e.y = expf(sv.y - mx);
    e.z = expf(sv.z - mx); e.w = expf(sv.w - mx);
    float s = e.x + e.y + e.z + e.w;
    s = wave_reduce_sum(s);
    if (lane == 0) lds[wid] = s;
    __syncthreads();
    if (tid == 0) {
        float t = 0.f;
        #pragma unroll
        for (int i = 0; i < 16; ++i) t += lds[i];
        s_sum = t;
    }
    __syncthreads();
    const float inv = 1.f / s_sum;
    float4 o = make_float4(e.x*inv, e.y*inv, e.z*inv, e.w*inv);
    ((float4*)(ws + WS_ATTW))[tid] = o;
    ((float4*)out_attw)[tid] = o;
    ws[WS_CTX + tid] = 0.f;   // zero context accumulator (ws is 0xAA-poisoned)
}

// E: ctx[k] = sum_s w[s]*enc[s,k] — 32 blocks of 128 s-rows, atomicAdd partials
__global__ void attn_context_kernel(const float* __restrict__ enc,
                                    float* __restrict__ ws) {
    const int tid = threadIdx.x;          // 256 thr -> 4 k's each (float4)
    const int s0 = blockIdx.x * 128;
    float4 acc = make_float4(0.f, 0.f, 0.f, 0.f);
    for (int s = s0; s < s0 + 128; ++s) {
        const float wgt = ws[WS_ATTW + s];
        float4 ev = ((const float4*)(enc + (long)s * H))[tid];
        acc.x += wgt * ev.x; acc.y += wgt * ev.y;
        acc.z += wgt * ev.z; acc.w += wgt * ev.w;
    }
    float* ctx = ws + WS_CTX + tid * 4;
    atomicAdd(ctx + 0, acc.x); atomicAdd(ctx + 1, acc.y);
    atomicAdd(ctx + 2, acc.z); atomicAdd(ctx + 3, acc.w);
}

// F: logits[v] = [h_new, ctx] @ W_out[v,:] + b_out[v] — 1 wave/row, 4 rows/block
__global__ void out_proj_kernel(const float* __restrict__ W_out,
                                const float* __restrict__ b_out,
                                float* __restrict__ ws,
                                float* __restrict__ out_ctx) {
    const int tid = threadIdx.x;
    const int lane = tid & 63, wid = tid >> 6;
    const int v = blockIdx.x * 4 + wid;
    const float4* Wr = (const float4*)(W_out + (long)v * I2);
    const float4* h4 = (const float4*)(ws + WS_HNEW);
    const float4* c4 = (const float4*)(ws + WS_CTX);
    float acc = 0.f;
    #pragma unroll
    for (int r = 0; r < 8; ++r) {
        const int idx = lane + r * 64;            // float4 idx in [0,512)
        float4 wv = Wr[idx];
        float4 jv = (r < 4) ? h4[idx] : c4[idx - 256];
        acc += wv.x*jv.x + wv.y*jv.y + wv.z*jv.z + wv.w*jv.w;
    }
    acc = wave_reduce_sum(acc);
    if (lane == 0) ws[WS_LOGITS + v] = acc + b_out[v];
    if (blockIdx.x == 0) {                        // piggyback: ctx -> d_out
        for (int k = tid; k < H; k += 256) out_ctx[k] = ws[WS_CTX + k];
    }
}

// G: logsumexp over 32000 logits (1 block, 1024 threads)
__global__ void lse_kernel(float* __restrict__ ws) {
    __shared__ float lds[16];
    __shared__ float s_max;
    const int tid = threadIdx.x;
    const int lane = tid & 63, wid = tid >> 6;
    const float* lg = ws + WS_LOGITS;
    float m = -INFINITY;
    for (int v = tid; v < VOCAB; v += 1024) m = fmaxf(m, lg[v]);
    m = wave_reduce_max(m);
    if (lane == 0) lds[wid] = m;
    __syncthreads();
    if (tid == 0) {
        float mm = lds[0];
        #pragma unroll
        for (int i = 1; i < 16; ++i) mm = fmaxf(mm, lds[i]);
        s_max = mm;
    }
    __syncthreads();
    const float mx = s_max;
    float s = 0.f;
    for (int v = tid; v < VOCAB; v += 1024) s += expf(lg[v] - mx);
    s = wave_reduce_sum(s);
    if (lane == 0) lds[wid] = s;
    __syncthreads();
    if (tid == 0) {
        float t = 0.f;
        #pragma unroll
        for (int i = 0; i < 16; ++i) t += lds[i];
        ws[WS_STATS] = mx + logf(t);
    }
}

// H: out[v] = logits[v] - lse
__global__ void logsoftmax_write_kernel(const float* __restrict__ ws,
                                        float* __restrict__ out) {
    const int v = blockIdx.x * 256 + threadIdx.x;
    if (v < VOCAB) out[v] = ws[WS_LOGITS + v] - ws[WS_STATS];
}

extern "C" void kernel_launch(void* const* d_in, const int* in_sizes, int n_in,
                              void* d_out, int out_size, void* d_ws, size_t ws_size,
                              hipStream_t stream) {
    const int*   word     = (const int*)  d_in[0];
    const float* last_ctx = (const float*)d_in[1];
    const float* prev_h   = (const float*)d_in[2];
    const float* enc      = (const float*)d_in[3];
    const float* emb      = (const float*)d_in[4];
    const float* W_ih     = (const float*)d_in[5];
    const float* W_hh     = (const float*)d_in[6];
    const float* b_ih     = (const float*)d_in[7];
    const float* b_hh     = (const float*)d_in[8];
    const float* W_out    = (const float*)d_in[9];
    const float* b_out    = (const float*)d_in[10];
    float* out = (float*)d_out;
    float* ws  = (float*)d_ws;

    gru_matvec_kernel<<<G3, 256, 0, stream>>>(word, last_ctx, prev_h, emb,
                                              W_ih, W_hh, b_ih, b_hh, ws);
    gru_gates_kernel<<<1, 1024, 0, stream>>>(prev_h, ws, out + OUT_HID);
    attn_scores_kernel<<<SRC, 256, 0, stream>>>(enc, ws, ws);
    attn_softmax_kernel<<<1, 1024, 0, stream>>>(ws, out + OUT_ATTW);
    attn_context_kernel<<<32, 256, 0, stream>>>(enc, ws);
    out_proj_kernel<<<VOCAB / 4, 256, 0, stream>>>(W_out, b_out, ws, out + OUT_CTX);
    lse_kernel<<<1, 1024, 0, stream>>>(ws);
    logsoftmax_write_kernel<<<(VOCAB + 255) / 256, 256, 0, stream>>>(ws, out);
}

// Round 4
// 455.666 us; speedup vs baseline: 1.0437x; 1.0437x over previous
//
#include <hip/hip_runtime.h>
#include <math.h>

#define H      1024
#define I2     2048
#define G3     3072
#define SRC    4096
#define VOCAB  32000

// d_out layout: [0,32000) log_softmax | [32000,33024) attn_context
//               [33024,34048) h_new   | [34048,38144) attn_weights
#define OUT_CTX   32000
#define OUT_HID   33024
#define OUT_ATTW  34048

// ws layout (floats)
#define WS_GI     0        // 3072
#define WS_GH     3072     // 3072
#define WS_HNEW   6144     // 1024
#define WS_SCORES 7168     // 4096
#define WS_CTX    15360    // 1024
#define WS_LOGITS 16384    // 32000
#define WS_STATS  48384    // 1 (logsumexp)

__device__ __forceinline__ float wave_reduce_sum(float v) {
    #pragma unroll
    for (int off = 32; off > 0; off >>= 1)
        v += __shfl_down(v, off, 64);
    return v;
}

__device__ __forceinline__ float wave_reduce_max(float v) {
    #pragma unroll
    for (int off = 32; off > 0; off >>= 1)
        v = fmaxf(v, __shfl_down(v, off, 64));
    return v;
}

typedef float vfloat4 __attribute__((ext_vector_type(4)));

__device__ __forceinline__ float4 nt_load4(const float4* p) {
    vfloat4 v = __builtin_nontemporal_load((const vfloat4*)p);
    return make_float4(v.x, v.y, v.z, v.w);
}

// A: gi[j] = W_ih[j,:]@rnn_in + b_ih[j];  gh[j] = W_hh[j,:]@h + b_hh[j]
// one block (256 thr) per row j in [0,3072)
__global__ void gru_matvec_kernel(const int* __restrict__ word,
                                  const float* __restrict__ last_ctx,
                                  const float* __restrict__ prev_h,
                                  const float* __restrict__ emb,
                                  const float* __restrict__ W_ih,
                                  const float* __restrict__ W_hh,
                                  const float* __restrict__ b_ih,
                                  const float* __restrict__ b_hh,
                                  float* __restrict__ ws) {
    __shared__ float lds[8];
    const int j = blockIdx.x;
    const int tid = threadIdx.x;
    const int w = word[0];
    const float4* emb4 = (const float4*)(emb + (long)w * H);
    const float4* ctx4 = (const float4*)last_ctx;
    const float4* h4   = (const float4*)prev_h;

    // gi: row of W_ih (2048 f32 = 512 float4), read-once -> nontemporal
    const float4* Wi = (const float4*)(W_ih + (long)j * I2);
    float gi = 0.f;
    {
        float4 wv = nt_load4(&Wi[tid]);         // elems [0,1024) -> emb row
        float4 xv = emb4[tid];
        gi += wv.x*xv.x + wv.y*xv.y + wv.z*xv.z + wv.w*xv.w;
        wv = nt_load4(&Wi[tid + 256]);          // elems [1024,2048) -> last_context
        xv = ctx4[tid];
        gi += wv.x*xv.x + wv.y*xv.y + wv.z*xv.z + wv.w*xv.w;
    }
    // gh: row of W_hh (1024 f32 = 256 float4)
    const float4* Wh = (const float4*)(W_hh + (long)j * H);
    float gh;
    {
        float4 wv = nt_load4(&Wh[tid]);
        float4 hv = h4[tid];
        gh = wv.x*hv.x + wv.y*hv.y + wv.z*hv.z + wv.w*hv.w;
    }

    const int lane = tid & 63, wid = tid >> 6;
    gi = wave_reduce_sum(gi);
    gh = wave_reduce_sum(gh);
    if (lane == 0) { lds[wid] = gi; lds[4 + wid] = gh; }
    __syncthreads();
    if (tid == 0) {
        float gis = lds[0] + lds[1] + lds[2] + lds[3];
        float ghs = lds[4] + lds[5] + lds[6] + lds[7];
        ws[WS_GI + j] = gis + b_ih[j];
        ws[WS_GH + j] = ghs + b_hh[j];
    }
}

// B: GRU gates -> h_new (1 block, 1024 threads); also zero ctx accumulator
__global__ void gru_gates_kernel(const float* __restrict__ prev_h,
                                 float* __restrict__ ws,
                                 float* __restrict__ out_hid) {
    const int j = threadIdx.x;
    const float ir = ws[WS_GI + j],        hr = ws[WS_GH + j];
    const float iz = ws[WS_GI + H + j],    hz = ws[WS_GH + H + j];
    const float in_ = ws[WS_GI + 2*H + j], hn = ws[WS_GH + 2*H + j];
    const float r = 1.f / (1.f + expf(-(ir + hr)));
    const float z = 1.f / (1.f + expf(-(iz + hz)));
    const float n = tanhf(in_ + r * hn);
    const float h = prev_h[j];
    const float hnew = (1.f - z) * n + z * h;
    ws[WS_HNEW + j] = hnew;
    out_hid[j] = hnew;
    ws[WS_CTX + j] = 0.f;   // zero context accumulator (ws is 0xAA-poisoned)
}

// C: scores[s] = enc[s,:] @ h_new  — one block (256 thr) per s
__global__ void attn_scores_kernel(const float* __restrict__ enc,
                                   const float* __restrict__ ws_in,
                                   float* __restrict__ ws) {
    __shared__ float lds[4];
    const int s = blockIdx.x, tid = threadIdx.x;
    float4 ev = ((const float4*)(enc + (long)s * H))[tid];   // cached: re-read in attn_fused
    float4 hv = ((const float4*)(ws_in + WS_HNEW))[tid];
    float d = ev.x*hv.x + ev.y*hv.y + ev.z*hv.z + ev.w*hv.w;
    const int lane = tid & 63, wid = tid >> 6;
    d = wave_reduce_sum(d);
    if (lane == 0) lds[wid] = d;
    __syncthreads();
    if (tid == 0) ws[WS_SCORES + s] = lds[0] + lds[1] + lds[2] + lds[3];
}

// D+E fused: per-block redundant softmax (cheap: 16 exp/thread) + context slice.
// 128 blocks x 256 thr; block b owns s-rows [b*32, b*32+32); block 0 writes attw.
__global__ void attn_fused_kernel(const float* __restrict__ enc,
                                  float* __restrict__ ws,
                                  float* __restrict__ out_attw) {
    __shared__ float s_e[SRC];        // 16 KB exp values
    __shared__ float red[4];
    __shared__ float s_stat;
    const int tid = threadIdx.x;
    const int lane = tid & 63, wid = tid >> 6;
    const float4* sc4 = (const float4*)(ws + WS_SCORES);

    float4 sv[4];
    float m = -INFINITY;
    #pragma unroll
    for (int i = 0; i < 4; ++i) {
        sv[i] = sc4[tid + 256 * i];
        m = fmaxf(m, fmaxf(fmaxf(sv[i].x, sv[i].y), fmaxf(sv[i].z, sv[i].w)));
    }
    m = wave_reduce_max(m);
    if (lane == 0) red[wid] = m;
    __syncthreads();
    if (tid == 0) s_stat = fmaxf(fmaxf(red[0], red[1]), fmaxf(red[2], red[3]));
    __syncthreads();
    const float mx = s_stat;
    float sum = 0.f;
    #pragma unroll
    for (int i = 0; i < 4; ++i) {
        float4 e;
        e.x = expf(sv[i].x - mx); e.y = expf(sv[i].y - mx);
        e.z = expf(sv[i].z - mx); e.w = expf(sv[i].w - mx);
        ((float4*)s_e)[tid + 256 * i] = e;
        sum += e.x + e.y + e.z + e.w;
    }
    sum = wave_reduce_sum(sum);
    if (lane == 0) red[wid] = sum;
    __syncthreads();
    if (tid == 0) s_stat = red[0] + red[1] + red[2] + red[3];
    __syncthreads();
    const float inv = 1.f / s_stat;

    // context slice: 32 s-rows; thread tid owns k in [4*tid, 4*tid+4)
    const int s0 = blockIdx.x * 32;
    float4 acc = make_float4(0.f, 0.f, 0.f, 0.f);
    for (int s = s0; s < s0 + 32; ++s) {
        const float wgt = s_e[s] * inv;
        float4 ev = ((const float4*)(enc + (long)s * H))[tid];
        acc.x += wgt * ev.x; acc.y += wgt * ev.y;
        acc.z += wgt * ev.z; acc.w += wgt * ev.w;
    }
    float* ctx = ws + WS_CTX + tid * 4;
    atomicAdd(ctx + 0, acc.x); atomicAdd(ctx + 1, acc.y);
    atomicAdd(ctx + 2, acc.z); atomicAdd(ctx + 3, acc.w);

    if (blockIdx.x == 0) {   // attn weights -> d_out
        #pragma unroll
        for (int i = 0; i < 4; ++i) {
            float4 e = ((float4*)s_e)[tid + 256 * i];
            float4 o = make_float4(e.x * inv, e.y * inv, e.z * inv, e.w * inv);
            ((float4*)out_attw)[tid + 256 * i] = o;
        }
    }
}

// F: logits[v] = [h_new, ctx] @ W_out[v,:] + b_out[v]
// 2000 blocks x 256 thr; block handles 16 rows (4/wave); joined vec in LDS.
__global__ void out_proj_kernel(const float* __restrict__ W_out,
                                const float* __restrict__ b_out,
                                float* __restrict__ ws,
                                float* __restrict__ out_ctx) {
    __shared__ float4 s_j[512];       // 8 KB joined [h_new | ctx]
    const int tid = threadIdx.x;
    const int lane = tid & 63, wid = tid >> 6;
    s_j[tid]       = ((const float4*)(ws + WS_HNEW))[tid];
    s_j[256 + tid] = ((const float4*)(ws + WS_CTX))[tid];
    __syncthreads();

    const int vbase = blockIdx.x * 16 + wid * 4;
    #pragma unroll
    for (int rr = 0; rr < 4; ++rr) {
        const int v = vbase + rr;
        const float4* Wr = (const float4*)(W_out + (long)v * I2);
        float acc = 0.f;
        #pragma unroll
        for (int r = 0; r < 8; ++r) {
            float4 wv = nt_load4(&Wr[lane + r * 64]);
            float4 jv = s_j[lane + r * 64];
            acc += wv.x*jv.x + wv.y*jv.y + wv.z*jv.z + wv.w*jv.w;
        }
        acc = wave_reduce_sum(acc);
        if (lane == 0) ws[WS_LOGITS + v] = acc + b_out[v];
    }
    if (blockIdx.x == 0) {            // piggyback: ctx -> d_out (from LDS)
        ((float4*)out_ctx)[tid] = s_j[256 + tid];
    }
}

// G: logsumexp over 32000 logits (1 block, 1024 threads, float4)
__global__ void lse_kernel(float* __restrict__ ws) {
    __shared__ float lds[16];
    __shared__ float s_max;
    const int tid = threadIdx.x;
    const int lane = tid & 63, wid = tid >> 6;
    const float4* lg4 = (const float4*)(ws + WS_LOGITS);
    float m = -INFINITY;
    for (int i = tid; i < VOCAB / 4; i += 1024) {
        float4 v = lg4[i];
        m = fmaxf(m, fmaxf(fmaxf(v.x, v.y), fmaxf(v.z, v.w)));
    }
    m = wave_reduce_max(m);
    if (lane == 0) lds[wid] = m;
    __syncthreads();
    if (tid == 0) {
        float mm = lds[0];
        #pragma unroll
        for (int i = 1; i < 16; ++i) mm = fmaxf(mm, lds[i]);
        s_max = mm;
    }
    __syncthreads();
    const float mx = s_max;
    float s = 0.f;
    for (int i = tid; i < VOCAB / 4; i += 1024) {
        float4 v = lg4[i];
        s += expf(v.x - mx) + expf(v.y - mx) + expf(v.z - mx) + expf(v.w - mx);
    }
    s = wave_reduce_sum(s);
    if (lane == 0) lds[wid] = s;
    __syncthreads();
    if (tid == 0) {
        float t = 0.f;
        #pragma unroll
        for (int i = 0; i < 16; ++i) t += lds[i];
        ws[WS_STATS] = mx + logf(t);
    }
}

// H: out[v] = logits[v] - lse   (float4 grid-stride)
__global__ void logsoftmax_write_kernel(const float* __restrict__ ws,
                                        float* __restrict__ out) {
    const float lse = ws[WS_STATS];
    const float4* lg4 = (const float4*)(ws + WS_LOGITS);
    float4* out4 = (float4*)out;
    for (int i = blockIdx.x * 256 + threadIdx.x; i < VOCAB / 4; i += gridDim.x * 256) {
        float4 v = lg4[i];
        out4[i] = make_float4(v.x - lse, v.y - lse, v.z - lse, v.w - lse);
    }
}

extern "C" void kernel_launch(void* const* d_in, const int* in_sizes, int n_in,
                              void* d_out, int out_size, void* d_ws, size_t ws_size,
                              hipStream_t stream) {
    const int*   word     = (const int*)  d_in[0];
    const float* last_ctx = (const float*)d_in[1];
    const float* prev_h   = (const float*)d_in[2];
    const float* enc      = (const float*)d_in[3];
    const float* emb      = (const float*)d_in[4];
    const float* W_ih     = (const float*)d_in[5];
    const float* W_hh     = (const float*)d_in[6];
    const float* b_ih     = (const float*)d_in[7];
    const float* b_hh     = (const float*)d_in[8];
    const float* W_out    = (const float*)d_in[9];
    const float* b_out    = (const float*)d_in[10];
    float* out = (float*)d_out;
    float* ws  = (float*)d_ws;

    gru_matvec_kernel<<<G3, 256, 0, stream>>>(word, last_ctx, prev_h, emb,
                                              W_ih, W_hh, b_ih, b_hh, ws);
    gru_gates_kernel<<<1, 1024, 0, stream>>>(prev_h, ws, out + OUT_HID);
    attn_scores_kernel<<<SRC, 256, 0, stream>>>(enc, ws, ws);
    attn_fused_kernel<<<128, 256, 0, stream>>>(enc, ws, out + OUT_ATTW);
    out_proj_kernel<<<VOCAB / 16, 256, 0, stream>>>(W_out, b_out, ws, out + OUT_CTX);
    lse_kernel<<<1, 1024, 0, stream>>>(ws);
    logsoftmax_write_kernel<<<32, 256, 0, stream>>>(ws, out);
}